// Round 2
// baseline (4466.232 us; speedup 1.0000x reference)
//
#include <hip/hip_runtime.h>
#include <stdint.h>

#define T_LEN 2048

typedef __bf16 bf16x8 __attribute__((ext_vector_type(8)));
typedef float  f32x4  __attribute__((ext_vector_type(4)));

typedef const __attribute__((address_space(1))) void* as1_cvp;
typedef __attribute__((address_space(3))) void* as3_vp;

union BF8 { unsigned short u[8]; bf16x8 v; uint4 q; };

__device__ __forceinline__ unsigned short f2bf(float f) {
  unsigned int u = __float_as_uint(f);
  u += 0x7FFFu + ((u >> 16) & 1u);            // RNE
  return (unsigned short)(u >> 16);
}
__device__ __forceinline__ float bf2f(unsigned short h) {
  return __uint_as_float(((unsigned int)h) << 16);
}

// ---------------- f32 -> bf16 bulk convert (8 elems/thread) ----------------
__global__ void conv_bf16_kernel(const float* __restrict__ in,
                                 unsigned short* __restrict__ out, int n8) {
  const int i = blockIdx.x * 256 + threadIdx.x;
  if (i >= n8) return;
  const float4 a = ((const float4*)in)[i * 2];
  const float4 b = ((const float4*)in)[i * 2 + 1];
  BF8 t;
  t.u[0]=f2bf(a.x); t.u[1]=f2bf(a.y); t.u[2]=f2bf(a.z); t.u[3]=f2bf(a.w);
  t.u[4]=f2bf(b.x); t.u[5]=f2bf(b.y); t.u[6]=f2bf(b.z); t.u[7]=f2bf(b.w);
  ((uint4*)out)[i] = t.q;
}

// ------------- transpose+convert: out[n][k] (bf16) = in[k][n] (f32) --------
__global__ void conv_T_kernel(const float* __restrict__ in,
                              unsigned short* __restrict__ out, int N, int K) {
  const int k8 = K >> 3;
  const int t = blockIdx.x * 256 + threadIdx.x;
  if (t >= N * k8) return;
  const int n = t / k8, k0 = (t - n * k8) << 3;
  BF8 o;
  #pragma unroll
  for (int i = 0; i < 8; ++i) o.u[i] = f2bf(in[(size_t)(k0 + i) * N + n]);
  *(uint4*)&out[(size_t)n * K + k0] = o.q;
}

// ---------------- bf16 GEMM: C[M,N] = A[M,K] * Bt[N,K]^T (+bias[,+resid]) ---
// MODE 0: C is bf16, no residual.  MODE 1: C is f32, += resid[row*N+col].
template<int MODE>
__global__ __launch_bounds__(256, 2)
void gemm_bt_kernel(const unsigned short* __restrict__ A,
                    const unsigned short* __restrict__ Bt,
                    const float* __restrict__ bias,
                    const float* __restrict__ resid,
                    void* __restrict__ Cv,
                    int M, int N, int K) {
  __shared__ unsigned short As[128 * 64];
  __shared__ unsigned short Bs[128 * 64];
  const int tid  = threadIdx.x;
  const int wave = tid >> 6, lane = tid & 63;
  const int lq = lane >> 4, lr = lane & 15;
  const int wr = wave >> 1, wc = wave & 1;
  const int m0 = blockIdx.y * 128, n0 = blockIdx.x * 128;

  f32x4 acc[4][4] = {};

  for (int k0 = 0; k0 < K; k0 += 64) {
    #pragma unroll
    for (int i = 0; i < 4; ++i) {
      const int c = i * 256 + tid;                 // 16B chunk id, 0..1023
      const int crow = c >> 3, ccol = (c & 7) << 3;
      const unsigned short* ga = A  + (size_t)(m0 + crow) * K + (k0 + ccol);
      const unsigned short* gb = Bt + (size_t)(n0 + crow) * K + (k0 + ccol);
      __builtin_amdgcn_global_load_lds((as1_cvp)(const void*)ga,
          (as3_vp)(void*)(As + (i * 256 + wave * 64) * 8), 16, 0, 0);
      __builtin_amdgcn_global_load_lds((as1_cvp)(const void*)gb,
          (as3_vp)(void*)(Bs + (i * 256 + wave * 64) * 8), 16, 0, 0);
    }
    __syncthreads();
    #pragma unroll
    for (int kt = 0; kt < 2; ++kt) {
      BF8 a[4], b[4];
      #pragma unroll
      for (int m = 0; m < 4; ++m)
        a[m].q = *(const uint4*)&As[(wr * 64 + m * 16 + lr) * 64 + kt * 32 + lq * 8];
      #pragma unroll
      for (int n = 0; n < 4; ++n)
        b[n].q = *(const uint4*)&Bs[(wc * 64 + n * 16 + lr) * 64 + kt * 32 + lq * 8];
      #pragma unroll
      for (int m = 0; m < 4; ++m)
        #pragma unroll
        for (int n = 0; n < 4; ++n)
          acc[m][n] = __builtin_amdgcn_mfma_f32_16x16x32_bf16(a[m].v, b[n].v, acc[m][n], 0, 0, 0);
    }
    __syncthreads();
  }

  #pragma unroll
  for (int m = 0; m < 4; ++m) {
    #pragma unroll
    for (int n = 0; n < 4; ++n) {
      const int col = n0 + wc * 64 + n * 16 + lr;
      const float bv = bias[col];
      #pragma unroll
      for (int j = 0; j < 4; ++j) {
        const int row = m0 + wr * 64 + m * 16 + lq * 4 + j;
        float v = acc[m][n][j] + bv;
        if (MODE == 0) {
          ((unsigned short*)Cv)[(size_t)row * N + col] = f2bf(v);
        } else {
          v += resid[(size_t)row * N + col];
          ((float*)Cv)[(size_t)row * N + col] = v;
        }
      }
    }
  }
}

// ---------------- sequential reservoir scan -------------------------------
// grid = 4 (one block per reservoir r), 256 threads (4 waves).
// Wave w owns output neurons k in [64w, 64w+64) for all 4 batches (M=4 rows
// of each 16x16x32 MFMA).  W_r held as B-fragments in VGPRs (bf16).
__global__ __launch_bounds__(256, 1)
void scan_kernel(const unsigned short* __restrict__ x,   // [B*T][1024] bf16
                 const float* __restrict__ prev,          // [B][1024] f32
                 const float* __restrict__ w_res,         // [4][256][256] f32
                 unsigned short* __restrict__ states,     // [B*T][1024] bf16
                 float* __restrict__ final_out) {         // [B][1024] f32
  const int r    = blockIdx.x;
  const int tid  = threadIdx.x;
  const int wave = tid >> 6, lane = tid & 63;
  const int lq   = lane >> 4, lr = lane & 15;
  const bool act = (lane < 16);

  __shared__ unsigned short st_lds[2][4][264];   // [buf][batch][neuron] (+pad)

  // --- W fragments: bw[nt][kt]; lane holds B[k=kt*32+lq*8+i][n=64*wave+16*nt+lr]
  //     where B[j][n] = W[n][j] = w_res[r][n][j]  (8 contiguous j per lane)
  BF8 bw[4][8];
  {
    const float* wbase = w_res + (size_t)r * 65536;
    #pragma unroll
    for (int nt = 0; nt < 4; ++nt) {
      const int n = wave * 64 + nt * 16 + lr;
      #pragma unroll
      for (int kt = 0; kt < 8; ++kt) {
        const float* s = wbase + n * 256 + kt * 32 + lq * 8;
        const float4 f0 = *(const float4*)s;
        const float4 f1 = *(const float4*)(s + 4);
        BF8 t;
        t.u[0]=f2bf(f0.x); t.u[1]=f2bf(f0.y); t.u[2]=f2bf(f0.z); t.u[3]=f2bf(f0.w);
        t.u[4]=f2bf(f1.x); t.u[5]=f2bf(f1.y); t.u[6]=f2bf(f1.z); t.u[7]=f2bf(f1.w);
        bw[nt][kt] = t;
      }
    }
  }

  // --- init state LDS buffer 0 with prev_state
  for (int idx = tid; idx < 1024; idx += 256) {
    const int b = idx >> 8, j = idx & 255;
    st_lds[0][b][j] = f2bf(prev[b * 1024 + r * 256 + j]);
  }

  // --- per-lane f32 master state + x/state pointers (lanes 0..15 only)
  float stf[4][4];                   // [nt][b]
  float xr[4][4];                    // prefetched x_t, [nt][b]
  const unsigned short* xb[4];
  unsigned short* sb[4];
  if (act) {
    #pragma unroll
    for (int b = 0; b < 4; ++b) {
      xb[b] = x      + (size_t)b * T_LEN * 1024 + r * 256 + wave * 64 + lr;
      sb[b] = states + (size_t)b * T_LEN * 1024 + r * 256 + wave * 64 + lr;
      #pragma unroll
      for (int nt = 0; nt < 4; ++nt) {
        stf[nt][b] = prev[b * 1024 + r * 256 + wave * 64 + nt * 16 + lr];
        xr[nt][b]  = bf2f(xb[b][nt * 16]);
      }
    }
  }

  bf16x8 af[8] = {};   // rows 4..15 stay zero forever (lanes with lr>=4)
  int cur = 0;

  for (int t = 0; t < T_LEN; ++t) {
    // raw barrier: drain LDS only (keep global loads/stores in flight)
    asm volatile("s_waitcnt lgkmcnt(0)" ::: "memory");
    __builtin_amdgcn_s_barrier();
    asm volatile("" ::: "memory");

    // A fragments from current state buffer (16 lanes with lr<4 carry rows 0..3)
    #pragma unroll
    for (int kt = 0; kt < 8; ++kt) {
      if (lr < 4) {
        BF8 tmp;
        tmp.q = *(const uint4*)&st_lds[cur][lr][kt * 32 + lq * 8];
        af[kt] = tmp.v;
      }
    }

    // acc = x_t (C rows 0..3 live in lanes 0..15, reg j = batch)
    f32x4 acc[4];
    #pragma unroll
    for (int nt = 0; nt < 4; ++nt) {
      f32x4 z = {0.f, 0.f, 0.f, 0.f};
      if (act) { z[0]=xr[nt][0]; z[1]=xr[nt][1]; z[2]=xr[nt][2]; z[3]=xr[nt][3]; }
      acc[nt] = z;
    }

    // prefetch x_{t+1} (overlaps with MFMAs below)
    const int adv = (t + 1 < T_LEN) ? 1024 : 0;
    if (act) {
      #pragma unroll
      for (int b = 0; b < 4; ++b) {
        xb[b] += adv;
        #pragma unroll
        for (int nt = 0; nt < 4; ++nt) xr[nt][b] = bf2f(xb[b][nt * 16]);
      }
    }

    // pre = state @ W^T + x
    #pragma unroll
    for (int kt = 0; kt < 8; ++kt) {
      #pragma unroll
      for (int nt = 0; nt < 4; ++nt)
        acc[nt] = __builtin_amdgcn_mfma_f32_16x16x32_bf16(af[kt], bw[nt][kt].v, acc[nt], 0, 0, 0);
    }

    // state update, write next LDS buffer + streamed bf16 states
    const int nxt = cur ^ 1;
    if (act) {
      #pragma unroll
      for (int nt = 0; nt < 4; ++nt) {
        #pragma unroll
        for (int b = 0; b < 4; ++b) {
          const float pre = acc[nt][b];
          const float e   = __expf(2.0f * pre);
          const float th  = 1.0f - 2.0f / (e + 1.0f);   // tanh, saturates safely
          const float ns  = 0.9f * stf[nt][b] + 0.1f * th;
          stf[nt][b] = ns;
          const unsigned short h = f2bf(ns);
          st_lds[nxt][b][wave * 64 + nt * 16 + lr] = h;
          sb[b][nt * 16] = h;
          if (t == T_LEN - 1)
            final_out[b * 1024 + r * 256 + wave * 64 + nt * 16 + lr] = ns;
        }
      }
      #pragma unroll
      for (int b = 0; b < 4; ++b) sb[b] += 1024;
    }
    cur = nxt;
  }
}

// ---------------- in-place RMSNorm over rows of 2048 ----------------------
__global__ __launch_bounds__(256, 4)
void rmsnorm_kernel(float* __restrict__ y, const float* __restrict__ lnw) {
  const int row = blockIdx.x;
  float* p = y + (size_t)row * 2048;
  const int tid = threadIdx.x;
  const int wave = tid >> 6, lane = tid & 63;
  float4 a = ((const float4*)p)[tid * 2];
  float4 b = ((const float4*)p)[tid * 2 + 1];
  float ss = a.x*a.x + a.y*a.y + a.z*a.z + a.w*a.w
           + b.x*b.x + b.y*b.y + b.z*b.z + b.w*b.w;
  #pragma unroll
  for (int m = 32; m >= 1; m >>= 1) ss += __shfl_xor(ss, m, 64);
  __shared__ float red[4];
  if (lane == 0) red[wave] = ss;
  __syncthreads();
  const float tot = red[0] + red[1] + red[2] + red[3];
  const float sc = rsqrtf(tot * (1.0f / 2048.0f) + 1e-6f);
  const float4 la = ((const float4*)lnw)[tid * 2];
  const float4 lb = ((const float4*)lnw)[tid * 2 + 1];
  a.x *= sc * la.x; a.y *= sc * la.y; a.z *= sc * la.z; a.w *= sc * la.w;
  b.x *= sc * lb.x; b.y *= sc * lb.y; b.z *= sc * lb.z; b.w *= sc * lb.w;
  ((float4*)p)[tid * 2] = a;
  ((float4*)p)[tid * 2 + 1] = b;
}

// --------------------------------------------------------------------------
extern "C" void kernel_launch(void* const* d_in, const int* in_sizes, int n_in,
                              void* d_out, int out_size, void* d_ws, size_t ws_size,
                              hipStream_t stream) {
  const float* hs    = (const float*)d_in[0];  // [4,2048,2048]
  const float* prev  = (const float*)d_in[1];  // [4,1024]
  const float* w_in  = (const float*)d_in[2];  // [2048,1024]
  const float* b_in  = (const float*)d_in[3];  // [1024]
  const float* w_res = (const float*)d_in[4];  // [4,256,256]
  const float* w_out = (const float*)d_in[5];  // [1024,2048]
  const float* b_out = (const float*)d_in[6];  // [2048]
  const float* ln_w  = (const float*)d_in[7];  // [2048]
  float* out = (float*)d_out;                  // y[8192*2048] then final[4096]

  char* ws = (char*)d_ws;
  unsigned short* hs_bf   = (unsigned short*)(ws);              // 32 MiB
  unsigned short* x_bf    = (unsigned short*)(ws + 33554432);   // 16 MiB
  unsigned short* states  = (unsigned short*)(ws + 50331648);   // 16 MiB
  unsigned short* w_in_t  = (unsigned short*)(ws + 67108864);   //  4 MiB
  unsigned short* w_out_t = (unsigned short*)(ws + 71303168);   //  4 MiB

  // 1. convert hidden_states to bf16
  conv_bf16_kernel<<<dim3(8192), dim3(256), 0, stream>>>(hs, hs_bf, 2097152);
  // 2. transposed bf16 weights (K-major for MFMA B-fragments)
  conv_T_kernel<<<dim3(1024), dim3(256), 0, stream>>>(w_in,  w_in_t,  1024, 2048);
  conv_T_kernel<<<dim3(1024), dim3(256), 0, stream>>>(w_out, w_out_t, 2048, 1024);
  // 3. x = hs @ w_in + b_in   (bf16 out)
  gemm_bt_kernel<0><<<dim3(8, 64), dim3(256), 0, stream>>>(
      hs_bf, w_in_t, b_in, nullptr, (void*)x_bf, 8192, 1024, 2048);
  // 4. sequential reservoir scan (writes states bf16 + final_state f32)
  scan_kernel<<<dim3(4), dim3(256), 0, stream>>>(
      x_bf, prev, w_res, states, out + 16777216);
  // 5. y_pre = hs + states @ w_out + b_out  (f32, into d_out)
  gemm_bt_kernel<1><<<dim3(16, 64), dim3(256), 0, stream>>>(
      states, w_out_t, b_out, hs, (void*)out, 8192, 2048, 1024);
  // 6. in-place RMSNorm * ln_w
  rmsnorm_kernel<<<dim3(8192), dim3(256), 0, stream>>>(out, ln_w);
}

// Round 4
// 2014.341 us; speedup vs baseline: 2.2172x; 2.2172x over previous
//
#include <hip/hip_runtime.h>
#include <stdint.h>

#define T_LEN 2048

typedef __bf16 bf16x8 __attribute__((ext_vector_type(8)));
typedef float  f32x4  __attribute__((ext_vector_type(4)));

typedef const __attribute__((address_space(1))) void* as1_cvp;
typedef __attribute__((address_space(3))) void* as3_vp;

union BF8 { unsigned short u[8]; bf16x8 v; uint4 q; };

__device__ __forceinline__ unsigned short f2bf(float f) {
  unsigned int u = __float_as_uint(f);
  u += 0x7FFFu + ((u >> 16) & 1u);            // RNE
  return (unsigned short)(u >> 16);
}
__device__ __forceinline__ float bf2f(unsigned short h) {
  return __uint_as_float(((unsigned int)h) << 16);
}

// ---------------- f32 -> bf16 bulk convert (8 elems/thread) ----------------
__global__ void conv_bf16_kernel(const float* __restrict__ in,
                                 unsigned short* __restrict__ out, int n8) {
  const int i = blockIdx.x * 256 + threadIdx.x;
  if (i >= n8) return;
  const float4 a = ((const float4*)in)[i * 2];
  const float4 b = ((const float4*)in)[i * 2 + 1];
  BF8 t;
  t.u[0]=f2bf(a.x); t.u[1]=f2bf(a.y); t.u[2]=f2bf(a.z); t.u[3]=f2bf(a.w);
  t.u[4]=f2bf(b.x); t.u[5]=f2bf(b.y); t.u[6]=f2bf(b.z); t.u[7]=f2bf(b.w);
  ((uint4*)out)[i] = t.q;
}

// ------------- transpose+convert: out[n][k] (bf16) = in[k][n] (f32) --------
__global__ void conv_T_kernel(const float* __restrict__ in,
                              unsigned short* __restrict__ out, int N, int K) {
  const int k8 = K >> 3;
  const int t = blockIdx.x * 256 + threadIdx.x;
  if (t >= N * k8) return;
  const int n = t / k8, k0 = (t - n * k8) << 3;
  BF8 o;
  #pragma unroll
  for (int i = 0; i < 8; ++i) o.u[i] = f2bf(in[(size_t)(k0 + i) * N + n]);
  *(uint4*)&out[(size_t)n * K + k0] = o.q;
}

// ---------------- bf16 GEMM: C[M,N] = A[M,K] * Bt[N,K]^T (+bias[,+resid]) ---
// MODE 0: C is bf16, no residual.  MODE 1: C is f32, += resid[row*N+col].
template<int MODE>
__global__ __launch_bounds__(256, 2)
void gemm_bt_kernel(const unsigned short* __restrict__ A,
                    const unsigned short* __restrict__ Bt,
                    const float* __restrict__ bias,
                    const float* __restrict__ resid,
                    void* __restrict__ Cv,
                    int M, int N, int K) {
  __shared__ unsigned short As[128 * 64];
  __shared__ unsigned short Bs[128 * 64];
  const int tid  = threadIdx.x;
  const int wave = tid >> 6, lane = tid & 63;
  const int lq = lane >> 4, lr = lane & 15;
  const int wr = wave >> 1, wc = wave & 1;
  const int m0 = blockIdx.y * 128, n0 = blockIdx.x * 128;

  f32x4 acc[4][4] = {};

  for (int k0 = 0; k0 < K; k0 += 64) {
    #pragma unroll
    for (int i = 0; i < 4; ++i) {
      const int c = i * 256 + tid;                 // 16B chunk id, 0..1023
      const int crow = c >> 3, ccol = (c & 7) << 3;
      const unsigned short* ga = A  + (size_t)(m0 + crow) * K + (k0 + ccol);
      const unsigned short* gb = Bt + (size_t)(n0 + crow) * K + (k0 + ccol);
      __builtin_amdgcn_global_load_lds((as1_cvp)(const void*)ga,
          (as3_vp)(void*)(As + (i * 256 + wave * 64) * 8), 16, 0, 0);
      __builtin_amdgcn_global_load_lds((as1_cvp)(const void*)gb,
          (as3_vp)(void*)(Bs + (i * 256 + wave * 64) * 8), 16, 0, 0);
    }
    __syncthreads();
    #pragma unroll
    for (int kt = 0; kt < 2; ++kt) {
      BF8 a[4], b[4];
      #pragma unroll
      for (int m = 0; m < 4; ++m)
        a[m].q = *(const uint4*)&As[(wr * 64 + m * 16 + lr) * 64 + kt * 32 + lq * 8];
      #pragma unroll
      for (int n = 0; n < 4; ++n)
        b[n].q = *(const uint4*)&Bs[(wc * 64 + n * 16 + lr) * 64 + kt * 32 + lq * 8];
      #pragma unroll
      for (int m = 0; m < 4; ++m)
        #pragma unroll
        for (int n = 0; n < 4; ++n)
          acc[m][n] = __builtin_amdgcn_mfma_f32_16x16x32_bf16(a[m].v, b[n].v, acc[m][n], 0, 0, 0);
    }
    __syncthreads();
  }

  #pragma unroll
  for (int m = 0; m < 4; ++m) {
    #pragma unroll
    for (int n = 0; n < 4; ++n) {
      const int col = n0 + wc * 64 + n * 16 + lr;
      const float bv = bias[col];
      #pragma unroll
      for (int j = 0; j < 4; ++j) {
        const int row = m0 + wr * 64 + m * 16 + lq * 4 + j;
        float v = acc[m][n][j] + bv;
        if (MODE == 0) {
          ((unsigned short*)Cv)[(size_t)row * N + col] = f2bf(v);
        } else {
          v += resid[(size_t)row * N + col];
          ((float*)Cv)[(size_t)row * N + col] = v;
        }
      }
    }
  }
}

// ---------------- sequential reservoir scan -------------------------------
// grid = 4 (one block per reservoir r), 256 threads (4 waves).
// Wave w owns output neurons n in [64w, 64w+64) for all 4 batches.
// Batch b is placed at MFMA A/C row 4b, so C row 4b = (lq=b, j=0): every
// lane owns exactly 4 (nt) outputs for batch lq -> update work uses all 64
// lanes (4x less wave-wide VALU than the rows-0..3 packing).
__global__ __launch_bounds__(256, 1)
void scan_kernel(const unsigned short* __restrict__ x,   // [B*T][1024] bf16
                 const float* __restrict__ prev,          // [B][1024] f32
                 const float* __restrict__ w_res,         // [4][256][256] f32
                 unsigned short* __restrict__ states,     // [B*T][1024] bf16
                 float* __restrict__ final_out) {         // [B][1024] f32
  const int r    = blockIdx.x;
  const int tid  = threadIdx.x;
  const int wave = tid >> 6, lane = tid & 63;
  const int lq   = lane >> 4, lr = lane & 15;

  // [buf][batch][neuron], stride 272 u16 (=136 dwords, ≡8 banks) so the 16
  // active A-read lanes (ab,lq) land pairwise ≤2-way on banks (2-way free).
  __shared__ unsigned short st_lds[2][4][272];

  // --- W fragments: bw[nt][kt]; lane holds B[k=kt*32+lq*8+i][n=64*wave+16*nt+lr]
  //     where B[j][n] = W[n][j] = w_res[r][n][j]
  BF8 bw[4][8];
  {
    const float* wbase = w_res + (size_t)r * 65536;
    #pragma unroll
    for (int nt = 0; nt < 4; ++nt) {
      const int n = wave * 64 + nt * 16 + lr;
      #pragma unroll
      for (int kt = 0; kt < 8; ++kt) {
        const float* s = wbase + n * 256 + kt * 32 + lq * 8;
        const float4 f0 = *(const float4*)s;
        const float4 f1 = *(const float4*)(s + 4);
        BF8 t;
        t.u[0]=f2bf(f0.x); t.u[1]=f2bf(f0.y); t.u[2]=f2bf(f0.z); t.u[3]=f2bf(f0.w);
        t.u[4]=f2bf(f1.x); t.u[5]=f2bf(f1.y); t.u[6]=f2bf(f1.z); t.u[7]=f2bf(f1.w);
        bw[nt][kt] = t;
      }
    }
  }

  // --- init state LDS buffer 0 with prev_state
  for (int idx = tid; idx < 1024; idx += 256) {
    const int b = idx >> 8, j = idx & 255;
    st_lds[0][b][j] = f2bf(prev[b * 1024 + r * 256 + j]);
  }

  // --- per-lane f32 master state + prefetched x: batch lq, neurons
  //     wave*64 + nt*16 + lr  (nt = 0..3)
  float stf[4], xr[4];
  const unsigned short* xp = x      + (size_t)lq * T_LEN * 1024 + r * 256 + wave * 64 + lr;
  unsigned short*       sp = states + (size_t)lq * T_LEN * 1024 + r * 256 + wave * 64 + lr;
  #pragma unroll
  for (int nt = 0; nt < 4; ++nt) {
    stf[nt] = prev[lq * 1024 + r * 256 + wave * 64 + nt * 16 + lr];
    xr[nt]  = bf2f(xp[nt * 16]);
  }

  // A fragments: lane&15 = row; rows {0,4,8,12} carry batch row/4, rest 0.
  bf16x8 af[8] = {};
  const bool aload = (lr & 3) == 0;
  const int  ab    = lr >> 2;
  int cur = 0;

  for (int t = 0; t < T_LEN; ++t) {
    // drain LDS only; keep global loads/stores in flight across the barrier
    asm volatile("s_waitcnt lgkmcnt(0)" ::: "memory");
    __builtin_amdgcn_s_barrier();
    asm volatile("" ::: "memory");

    #pragma unroll
    for (int kt = 0; kt < 8; ++kt) {
      if (aload) {
        BF8 tmp;
        tmp.q = *(const uint4*)&st_lds[cur][ab][kt * 32 + lq * 8];
        af[kt] = tmp.v;
      }
    }

    // acc row 4*lq (j=0) = x_t for batch lq; other rows stay 0
    f32x4 acc[4];
    #pragma unroll
    for (int nt = 0; nt < 4; ++nt) {
      f32x4 z = {xr[nt], 0.f, 0.f, 0.f};
      acc[nt] = z;
    }

    // prefetch x_{t+1} (overlaps with MFMAs below)
    const int adv = (t + 1 < T_LEN) ? 1024 : 0;
    xp += adv;
    #pragma unroll
    for (int nt = 0; nt < 4; ++nt) xr[nt] = bf2f(xp[nt * 16]);

    // pre = state @ W^T + x
    #pragma unroll
    for (int kt = 0; kt < 8; ++kt) {
      #pragma unroll
      for (int nt = 0; nt < 4; ++nt)
        acc[nt] = __builtin_amdgcn_mfma_f32_16x16x32_bf16(af[kt], bw[nt][kt].v, acc[nt], 0, 0, 0);
    }

    // state update (all 64 lanes, 4 values each)
    const int nxt = cur ^ 1;
    #pragma unroll
    for (int nt = 0; nt < 4; ++nt) {
      const float pre = acc[nt][0];
      const float e   = __expf(2.0f * pre);
      const float th  = 1.0f - 2.0f / (e + 1.0f);   // tanh, saturates safely
      const float ns  = 0.9f * stf[nt] + 0.1f * th;
      stf[nt] = ns;
      const unsigned short h = f2bf(ns);
      st_lds[nxt][lq][wave * 64 + nt * 16 + lr] = h;
      sp[nt * 16] = h;
      if (t == T_LEN - 1)
        final_out[lq * 1024 + r * 256 + wave * 64 + nt * 16 + lr] = ns;
    }
    sp += 1024;
    cur = nxt;
  }
}

// ---------------- in-place RMSNorm over rows of 2048 ----------------------
__global__ __launch_bounds__(256, 4)
void rmsnorm_kernel(float* __restrict__ y, const float* __restrict__ lnw) {
  const int row = blockIdx.x;
  float* p = y + (size_t)row * 2048;
  const int tid = threadIdx.x;
  const int wave = tid >> 6, lane = tid & 63;
  float4 a = ((const float4*)p)[tid * 2];
  float4 b = ((const float4*)p)[tid * 2 + 1];
  float ss = a.x*a.x + a.y*a.y + a.z*a.z + a.w*a.w
           + b.x*b.x + b.y*b.y + b.z*b.z + b.w*b.w;
  #pragma unroll
  for (int m = 32; m >= 1; m >>= 1) ss += __shfl_xor(ss, m, 64);
  __shared__ float red[4];
  if (lane == 0) red[wave] = ss;
  __syncthreads();
  const float tot = red[0] + red[1] + red[2] + red[3];
  const float sc = rsqrtf(tot * (1.0f / 2048.0f) + 1e-6f);
  const float4 la = ((const float4*)lnw)[tid * 2];
  const float4 lb = ((const float4*)lnw)[tid * 2 + 1];
  a.x *= sc * la.x; a.y *= sc * la.y; a.z *= sc * la.z; a.w *= sc * la.w;
  b.x *= sc * lb.x; b.y *= sc * lb.y; b.z *= sc * lb.z; b.w *= sc * lb.w;
  ((float4*)p)[tid * 2] = a;
  ((float4*)p)[tid * 2 + 1] = b;
}

// --------------------------------------------------------------------------
extern "C" void kernel_launch(void* const* d_in, const int* in_sizes, int n_in,
                              void* d_out, int out_size, void* d_ws, size_t ws_size,
                              hipStream_t stream) {
  const float* hs    = (const float*)d_in[0];  // [4,2048,2048]
  const float* prev  = (const float*)d_in[1];  // [4,1024]
  const float* w_in  = (const float*)d_in[2];  // [2048,1024]
  const float* b_in  = (const float*)d_in[3];  // [1024]
  const float* w_res = (const float*)d_in[4];  // [4,256,256]
  const float* w_out = (const float*)d_in[5];  // [1024,2048]
  const float* b_out = (const float*)d_in[6];  // [2048]
  const float* ln_w  = (const float*)d_in[7];  // [2048]
  float* out = (float*)d_out;                  // y[8192*2048] then final[4096]

  char* ws = (char*)d_ws;
  unsigned short* hs_bf   = (unsigned short*)(ws);              // 32 MiB
  unsigned short* x_bf    = (unsigned short*)(ws + 33554432);   // 16 MiB
  unsigned short* states  = (unsigned short*)(ws + 50331648);   // 16 MiB
  unsigned short* w_in_t  = (unsigned short*)(ws + 67108864);   //  4 MiB
  unsigned short* w_out_t = (unsigned short*)(ws + 71303168);   //  4 MiB

  // 1. convert hidden_states to bf16
  conv_bf16_kernel<<<dim3(8192), dim3(256), 0, stream>>>(hs, hs_bf, 2097152);
  // 2. transposed bf16 weights (K-major for MFMA B-fragments)
  conv_T_kernel<<<dim3(1024), dim3(256), 0, stream>>>(w_in,  w_in_t,  1024, 2048);
  conv_T_kernel<<<dim3(1024), dim3(256), 0, stream>>>(w_out, w_out_t, 2048, 1024);
  // 3. x = hs @ w_in + b_in   (bf16 out)
  gemm_bt_kernel<0><<<dim3(8, 64), dim3(256), 0, stream>>>(
      hs_bf, w_in_t, b_in, nullptr, (void*)x_bf, 8192, 1024, 2048);
  // 4. sequential reservoir scan (writes states bf16 + final_state f32)
  scan_kernel<<<dim3(4), dim3(256), 0, stream>>>(
      x_bf, prev, w_res, states, out + 16777216);
  // 5. y_pre = hs + states @ w_out + b_out  (f32, into d_out)
  gemm_bt_kernel<1><<<dim3(16, 64), dim3(256), 0, stream>>>(
      states, w_out_t, b_out, hs, (void*)out, 8192, 2048, 1024);
  // 6. in-place RMSNorm * ln_w
  rmsnorm_kernel<<<dim3(8192), dim3(256), 0, stream>>>(out, ln_w);
}

// Round 5
// 1514.600 us; speedup vs baseline: 2.9488x; 1.3299x over previous
//
#include <hip/hip_runtime.h>
#include <stdint.h>

#define T_LEN 2048

typedef __bf16 bf16x8 __attribute__((ext_vector_type(8)));
typedef float  f32x4  __attribute__((ext_vector_type(4)));

typedef const __attribute__((address_space(1))) void* as1_cvp;
typedef __attribute__((address_space(3))) void* as3_vp;

union BF8 { unsigned short u[8]; bf16x8 v; uint4 q; };

__device__ __forceinline__ unsigned short f2bf(float f) {
  unsigned int u = __float_as_uint(f);
  u += 0x7FFFu + ((u >> 16) & 1u);            // RNE
  return (unsigned short)(u >> 16);
}
__device__ __forceinline__ float bf2f(unsigned short h) {
  return __uint_as_float(((unsigned int)h) << 16);
}

// ---------------- f32 -> bf16 bulk convert (8 elems/thread) ----------------
__global__ void conv_bf16_kernel(const float* __restrict__ in,
                                 unsigned short* __restrict__ out, int n8) {
  const int i = blockIdx.x * 256 + threadIdx.x;
  if (i >= n8) return;
  const float4 a = ((const float4*)in)[i * 2];
  const float4 b = ((const float4*)in)[i * 2 + 1];
  BF8 t;
  t.u[0]=f2bf(a.x); t.u[1]=f2bf(a.y); t.u[2]=f2bf(a.z); t.u[3]=f2bf(a.w);
  t.u[4]=f2bf(b.x); t.u[5]=f2bf(b.y); t.u[6]=f2bf(b.z); t.u[7]=f2bf(b.w);
  ((uint4*)out)[i] = t.q;
}

// ------------- transpose+convert: out[n][k] (bf16) = in[k][n] (f32) --------
__global__ void conv_T_kernel(const float* __restrict__ in,
                              unsigned short* __restrict__ out, int N, int K) {
  const int k8 = K >> 3;
  const int t = blockIdx.x * 256 + threadIdx.x;
  if (t >= N * k8) return;
  const int n = t / k8, k0 = (t - n * k8) << 3;
  BF8 o;
  #pragma unroll
  for (int i = 0; i < 8; ++i) o.u[i] = f2bf(in[(size_t)(k0 + i) * N + n]);
  *(uint4*)&out[(size_t)n * K + k0] = o.q;
}

// ---------------- bf16 GEMM: C[M,N] = A[M,K] * Bt[N,K]^T (+bias[,+resid]) ---
// MODE 0: C is bf16, no residual.  MODE 1: C is f32, += resid[row*N+col].
template<int MODE>
__global__ __launch_bounds__(256, 2)
void gemm_bt_kernel(const unsigned short* __restrict__ A,
                    const unsigned short* __restrict__ Bt,
                    const float* __restrict__ bias,
                    const float* __restrict__ resid,
                    void* __restrict__ Cv,
                    int M, int N, int K) {
  __shared__ unsigned short As[128 * 64];
  __shared__ unsigned short Bs[128 * 64];
  const int tid  = threadIdx.x;
  const int wave = tid >> 6, lane = tid & 63;
  const int lq = lane >> 4, lr = lane & 15;
  const int wr = wave >> 1, wc = wave & 1;
  const int m0 = blockIdx.y * 128, n0 = blockIdx.x * 128;

  f32x4 acc[4][4] = {};

  for (int k0 = 0; k0 < K; k0 += 64) {
    #pragma unroll
    for (int i = 0; i < 4; ++i) {
      const int c = i * 256 + tid;                 // 16B chunk id, 0..1023
      const int crow = c >> 3, ccol = (c & 7) << 3;
      const unsigned short* ga = A  + (size_t)(m0 + crow) * K + (k0 + ccol);
      const unsigned short* gb = Bt + (size_t)(n0 + crow) * K + (k0 + ccol);
      __builtin_amdgcn_global_load_lds((as1_cvp)(const void*)ga,
          (as3_vp)(void*)(As + (i * 256 + wave * 64) * 8), 16, 0, 0);
      __builtin_amdgcn_global_load_lds((as1_cvp)(const void*)gb,
          (as3_vp)(void*)(Bs + (i * 256 + wave * 64) * 8), 16, 0, 0);
    }
    __syncthreads();
    #pragma unroll
    for (int kt = 0; kt < 2; ++kt) {
      BF8 a[4], b[4];
      #pragma unroll
      for (int m = 0; m < 4; ++m)
        a[m].q = *(const uint4*)&As[(wr * 64 + m * 16 + lr) * 64 + kt * 32 + lq * 8];
      #pragma unroll
      for (int n = 0; n < 4; ++n)
        b[n].q = *(const uint4*)&Bs[(wc * 64 + n * 16 + lr) * 64 + kt * 32 + lq * 8];
      #pragma unroll
      for (int m = 0; m < 4; ++m)
        #pragma unroll
        for (int n = 0; n < 4; ++n)
          acc[m][n] = __builtin_amdgcn_mfma_f32_16x16x32_bf16(a[m].v, b[n].v, acc[m][n], 0, 0, 0);
    }
    __syncthreads();
  }

  #pragma unroll
  for (int m = 0; m < 4; ++m) {
    #pragma unroll
    for (int n = 0; n < 4; ++n) {
      const int col = n0 + wc * 64 + n * 16 + lr;
      const float bv = bias[col];
      #pragma unroll
      for (int j = 0; j < 4; ++j) {
        const int row = m0 + wr * 64 + m * 16 + lq * 4 + j;
        float v = acc[m][n][j] + bv;
        if (MODE == 0) {
          ((unsigned short*)Cv)[(size_t)row * N + col] = f2bf(v);
        } else {
          v += resid[(size_t)row * N + col];
          ((float*)Cv)[(size_t)row * N + col] = v;
        }
      }
    }
  }
}

// ---------------- sequential reservoir scan -------------------------------
// grid = 4 (one block per reservoir r), 512 threads (8 waves, 2 per SIMD).
// Wave w owns output neurons n in [32w, 32w+32) for all 4 batches.
// Batch b sits at MFMA A/C row 4b, so C row 4b = (lq=b, j=0): every lane
// owns 2 (nt) outputs for batch lq.  2 waves/SIMD overlap latencies.
__global__ __launch_bounds__(512, 2)
void scan_kernel(const unsigned short* __restrict__ x,   // [B*T][1024] bf16
                 const float* __restrict__ prev,          // [B][1024] f32
                 const float* __restrict__ w_res,         // [4][256][256] f32
                 unsigned short* __restrict__ states,     // [B*T][1024] bf16
                 float* __restrict__ final_out) {         // [B][1024] f32
  const int r    = blockIdx.x;
  const int tid  = threadIdx.x;
  const int wave = tid >> 6, lane = tid & 63;
  const int lq   = lane >> 4, lr = lane & 15;

  // [buf][batch][neuron], stride 272 u16 so the 16 active A-read lanes land
  // pairwise <=2-way on banks (2-way is free, m136).
  __shared__ unsigned short st_lds[2][4][272];

  // --- W fragments: bw[nt][kt]; lane holds B[k=kt*32+lq*8+i][n=32*wave+16*nt+lr]
  //     where B[j][n] = W[n][j] = w_res[r][n][j]
  BF8 bw[2][8];
  {
    const float* wbase = w_res + (size_t)r * 65536;
    #pragma unroll
    for (int nt = 0; nt < 2; ++nt) {
      const int n = wave * 32 + nt * 16 + lr;
      #pragma unroll
      for (int kt = 0; kt < 8; ++kt) {
        const float* s = wbase + n * 256 + kt * 32 + lq * 8;
        const float4 f0 = *(const float4*)s;
        const float4 f1 = *(const float4*)(s + 4);
        BF8 t;
        t.u[0]=f2bf(f0.x); t.u[1]=f2bf(f0.y); t.u[2]=f2bf(f0.z); t.u[3]=f2bf(f0.w);
        t.u[4]=f2bf(f1.x); t.u[5]=f2bf(f1.y); t.u[6]=f2bf(f1.z); t.u[7]=f2bf(f1.w);
        bw[nt][kt] = t;
      }
    }
  }

  // --- init state LDS buffer 0 with prev_state
  for (int idx = tid; idx < 1024; idx += 512) {
    const int b = idx >> 8, j = idx & 255;
    st_lds[0][b][j] = f2bf(prev[b * 1024 + r * 256 + j]);
  }

  // --- per-lane f32 master state + prefetched x: batch lq, neurons
  //     wave*32 + nt*16 + lr  (nt = 0..1)
  float stf[2], xr[2];
  const unsigned short* xp = x      + (size_t)lq * T_LEN * 1024 + r * 256 + wave * 32 + lr;
  unsigned short*       sp = states + (size_t)lq * T_LEN * 1024 + r * 256 + wave * 32 + lr;
  #pragma unroll
  for (int nt = 0; nt < 2; ++nt) {
    stf[nt] = prev[lq * 1024 + r * 256 + wave * 32 + nt * 16 + lr];
    xr[nt]  = bf2f(xp[nt * 16]);
  }

  // A fragments: lane&15 = row; rows {0,4,8,12} carry batch row/4, rest 0.
  bf16x8 af[8] = {};
  const bool aload = (lr & 3) == 0;
  const int  ab    = lr >> 2;
  int cur = 0;

  for (int t = 0; t < T_LEN; ++t) {
    // drain LDS only; keep global loads/stores in flight across the barrier
    asm volatile("s_waitcnt lgkmcnt(0)" ::: "memory");
    __builtin_amdgcn_s_barrier();
    asm volatile("" ::: "memory");

    #pragma unroll
    for (int kt = 0; kt < 8; ++kt) {
      if (aload) {
        BF8 tmp;
        tmp.q = *(const uint4*)&st_lds[cur][ab][kt * 32 + lq * 8];
        af[kt] = tmp.v;
      }
    }

    // 4 independent accumulator chains (nt x kt-half), depth 4 each
    f32x4 acc[2][2];
    #pragma unroll
    for (int nt = 0; nt < 2; ++nt) {
      f32x4 z0 = {xr[nt], 0.f, 0.f, 0.f};
      f32x4 z1 = {0.f, 0.f, 0.f, 0.f};
      acc[nt][0] = z0;
      acc[nt][1] = z1;
    }

    // prefetch x_{t+1} (overlaps with MFMAs below)
    const int adv = (t + 1 < T_LEN) ? 1024 : 0;
    xp += adv;
    #pragma unroll
    for (int nt = 0; nt < 2; ++nt) xr[nt] = bf2f(xp[nt * 16]);

    // pre = state @ W^T + x   (interleave 4 chains for MFMA-latency ILP)
    #pragma unroll
    for (int kt = 0; kt < 4; ++kt) {
      #pragma unroll
      for (int nt = 0; nt < 2; ++nt) {
        acc[nt][0] = __builtin_amdgcn_mfma_f32_16x16x32_bf16(af[kt],     bw[nt][kt].v,     acc[nt][0], 0, 0, 0);
        acc[nt][1] = __builtin_amdgcn_mfma_f32_16x16x32_bf16(af[kt + 4], bw[nt][kt + 4].v, acc[nt][1], 0, 0, 0);
      }
    }

    // state update (all 64 lanes, 2 values each)
    const int nxt = cur ^ 1;
    #pragma unroll
    for (int nt = 0; nt < 2; ++nt) {
      const float pre = acc[nt][0][0] + acc[nt][1][0];
      const float e   = __expf(2.0f * pre);
      const float th  = 1.0f - 2.0f / (e + 1.0f);   // tanh, saturates safely
      const float ns  = 0.9f * stf[nt] + 0.1f * th;
      stf[nt] = ns;
      const unsigned short h = f2bf(ns);
      st_lds[nxt][lq][wave * 32 + nt * 16 + lr] = h;
      sp[nt * 16] = h;
    }
    sp += 1024;
    cur = nxt;
  }

  // final state (f32) from register copy
  #pragma unroll
  for (int nt = 0; nt < 2; ++nt)
    final_out[lq * 1024 + r * 256 + wave * 32 + nt * 16 + lr] = stf[nt];
}

// ---------------- in-place RMSNorm over rows of 2048 ----------------------
__global__ __launch_bounds__(256, 4)
void rmsnorm_kernel(float* __restrict__ y, const float* __restrict__ lnw) {
  const int row = blockIdx.x;
  float* p = y + (size_t)row * 2048;
  const int tid = threadIdx.x;
  const int wave = tid >> 6, lane = tid & 63;
  float4 a = ((const float4*)p)[tid * 2];
  float4 b = ((const float4*)p)[tid * 2 + 1];
  float ss = a.x*a.x + a.y*a.y + a.z*a.z + a.w*a.w
           + b.x*b.x + b.y*b.y + b.z*b.z + b.w*b.w;
  #pragma unroll
  for (int m = 32; m >= 1; m >>= 1) ss += __shfl_xor(ss, m, 64);
  __shared__ float red[4];
  if (lane == 0) red[wave] = ss;
  __syncthreads();
  const float tot = red[0] + red[1] + red[2] + red[3];
  const float sc = rsqrtf(tot * (1.0f / 2048.0f) + 1e-6f);
  const float4 la = ((const float4*)lnw)[tid * 2];
  const float4 lb = ((const float4*)lnw)[tid * 2 + 1];
  a.x *= sc * la.x; a.y *= sc * la.y; a.z *= sc * la.z; a.w *= sc * la.w;
  b.x *= sc * lb.x; b.y *= sc * lb.y; b.z *= sc * lb.z; b.w *= sc * lb.w;
  ((float4*)p)[tid * 2] = a;
  ((float4*)p)[tid * 2 + 1] = b;
}

// --------------------------------------------------------------------------
extern "C" void kernel_launch(void* const* d_in, const int* in_sizes, int n_in,
                              void* d_out, int out_size, void* d_ws, size_t ws_size,
                              hipStream_t stream) {
  const float* hs    = (const float*)d_in[0];  // [4,2048,2048]
  const float* prev  = (const float*)d_in[1];  // [4,1024]
  const float* w_in  = (const float*)d_in[2];  // [2048,1024]
  const float* b_in  = (const float*)d_in[3];  // [1024]
  const float* w_res = (const float*)d_in[4];  // [4,256,256]
  const float* w_out = (const float*)d_in[5];  // [1024,2048]
  const float* b_out = (const float*)d_in[6];  // [2048]
  const float* ln_w  = (const float*)d_in[7];  // [2048]
  float* out = (float*)d_out;                  // y[8192*2048] then final[4096]

  char* ws = (char*)d_ws;
  unsigned short* hs_bf   = (unsigned short*)(ws);              // 32 MiB
  unsigned short* x_bf    = (unsigned short*)(ws + 33554432);   // 16 MiB
  unsigned short* states  = (unsigned short*)(ws + 50331648);   // 16 MiB
  unsigned short* w_in_t  = (unsigned short*)(ws + 67108864);   //  4 MiB
  unsigned short* w_out_t = (unsigned short*)(ws + 71303168);   //  4 MiB

  // 1. convert hidden_states to bf16
  conv_bf16_kernel<<<dim3(8192), dim3(256), 0, stream>>>(hs, hs_bf, 2097152);
  // 2. transposed bf16 weights (K-major for MFMA B-fragments)
  conv_T_kernel<<<dim3(1024), dim3(256), 0, stream>>>(w_in,  w_in_t,  1024, 2048);
  conv_T_kernel<<<dim3(1024), dim3(256), 0, stream>>>(w_out, w_out_t, 2048, 1024);
  // 3. x = hs @ w_in + b_in   (bf16 out)
  gemm_bt_kernel<0><<<dim3(8, 64), dim3(256), 0, stream>>>(
      hs_bf, w_in_t, b_in, nullptr, (void*)x_bf, 8192, 1024, 2048);
  // 4. sequential reservoir scan (writes states bf16 + final_state f32)
  scan_kernel<<<dim3(4), dim3(512), 0, stream>>>(
      x_bf, prev, w_res, states, out + 16777216);
  // 5. y_pre = hs + states @ w_out + b_out  (f32, into d_out)
  gemm_bt_kernel<1><<<dim3(16, 64), dim3(256), 0, stream>>>(
      states, w_out_t, b_out, hs, (void*)out, 8192, 2048, 1024);
  // 6. in-place RMSNorm * ln_w
  rmsnorm_kernel<<<dim3(8192), dim3(256), 0, stream>>>(out, ln_w);
}

// Round 7
// 1439.441 us; speedup vs baseline: 3.1028x; 1.0522x over previous
//
#include <hip/hip_runtime.h>
#include <stdint.h>

#define T_LEN 2048

typedef __bf16 bf16x8 __attribute__((ext_vector_type(8)));
typedef float  f32x4  __attribute__((ext_vector_type(4)));

typedef const __attribute__((address_space(1))) void* as1_cvp;
typedef __attribute__((address_space(3))) void* as3_vp;

union BF8 { unsigned short u[8]; bf16x8 v; uint4 q; };

__device__ __forceinline__ unsigned short f2bf(float f) {
  unsigned int u = __float_as_uint(f);
  u += 0x7FFFu + ((u >> 16) & 1u);            // RNE
  return (unsigned short)(u >> 16);
}
__device__ __forceinline__ float bf2f(unsigned short h) {
  return __uint_as_float(((unsigned int)h) << 16);
}

// ---------------- f32 -> bf16 bulk convert (8 elems/thread) ----------------
__global__ void conv_bf16_kernel(const float* __restrict__ in,
                                 unsigned short* __restrict__ out, int n8) {
  const int i = blockIdx.x * 256 + threadIdx.x;
  if (i >= n8) return;
  const float4 a = ((const float4*)in)[i * 2];
  const float4 b = ((const float4*)in)[i * 2 + 1];
  BF8 t;
  t.u[0]=f2bf(a.x); t.u[1]=f2bf(a.y); t.u[2]=f2bf(a.z); t.u[3]=f2bf(a.w);
  t.u[4]=f2bf(b.x); t.u[5]=f2bf(b.y); t.u[6]=f2bf(b.z); t.u[7]=f2bf(b.w);
  ((uint4*)out)[i] = t.q;
}

// ------------- transpose+convert: out[n][k] (bf16) = in[k][n] (f32) --------
__global__ void conv_T_kernel(const float* __restrict__ in,
                              unsigned short* __restrict__ out, int N, int K) {
  const int k8 = K >> 3;
  const int t = blockIdx.x * 256 + threadIdx.x;
  if (t >= N * k8) return;
  const int n = t / k8, k0 = (t - n * k8) << 3;
  BF8 o;
  #pragma unroll
  for (int i = 0; i < 8; ++i) o.u[i] = f2bf(in[(size_t)(k0 + i) * N + n]);
  *(uint4*)&out[(size_t)n * K + k0] = o.q;
}

// ---------------- bf16 GEMM: C[M,N] = A[M,K] * Bt[N,K]^T (+bias[,+resid]) ---
// MODE 0: C is bf16, no residual.  MODE 1: C is f32, += resid[row*N+col].
template<int MODE>
__global__ __launch_bounds__(256, 2)
void gemm_bt_kernel(const unsigned short* __restrict__ A,
                    const unsigned short* __restrict__ Bt,
                    const float* __restrict__ bias,
                    const float* __restrict__ resid,
                    void* __restrict__ Cv,
                    int M, int N, int K) {
  __shared__ unsigned short As[128 * 64];
  __shared__ unsigned short Bs[128 * 64];
  const int tid  = threadIdx.x;
  const int wave = tid >> 6, lane = tid & 63;
  const int lq = lane >> 4, lr = lane & 15;
  const int wr = wave >> 1, wc = wave & 1;
  const int m0 = blockIdx.y * 128, n0 = blockIdx.x * 128;

  f32x4 acc[4][4] = {};

  for (int k0 = 0; k0 < K; k0 += 64) {
    #pragma unroll
    for (int i = 0; i < 4; ++i) {
      const int c = i * 256 + tid;                 // 16B chunk id, 0..1023
      const int crow = c >> 3, ccol = (c & 7) << 3;
      const unsigned short* ga = A  + (size_t)(m0 + crow) * K + (k0 + ccol);
      const unsigned short* gb = Bt + (size_t)(n0 + crow) * K + (k0 + ccol);
      __builtin_amdgcn_global_load_lds((as1_cvp)(const void*)ga,
          (as3_vp)(void*)(As + (i * 256 + wave * 64) * 8), 16, 0, 0);
      __builtin_amdgcn_global_load_lds((as1_cvp)(const void*)gb,
          (as3_vp)(void*)(Bs + (i * 256 + wave * 64) * 8), 16, 0, 0);
    }
    __syncthreads();
    #pragma unroll
    for (int kt = 0; kt < 2; ++kt) {
      BF8 a[4], b[4];
      #pragma unroll
      for (int m = 0; m < 4; ++m)
        a[m].q = *(const uint4*)&As[(wr * 64 + m * 16 + lr) * 64 + kt * 32 + lq * 8];
      #pragma unroll
      for (int n = 0; n < 4; ++n)
        b[n].q = *(const uint4*)&Bs[(wc * 64 + n * 16 + lr) * 64 + kt * 32 + lq * 8];
      #pragma unroll
      for (int m = 0; m < 4; ++m)
        #pragma unroll
        for (int n = 0; n < 4; ++n)
          acc[m][n] = __builtin_amdgcn_mfma_f32_16x16x32_bf16(a[m].v, b[n].v, acc[m][n], 0, 0, 0);
    }
    __syncthreads();
  }

  #pragma unroll
  for (int m = 0; m < 4; ++m) {
    #pragma unroll
    for (int n = 0; n < 4; ++n) {
      const int col = n0 + wc * 64 + n * 16 + lr;
      const float bv = bias[col];
      #pragma unroll
      for (int j = 0; j < 4; ++j) {
        const int row = m0 + wr * 64 + m * 16 + lq * 4 + j;
        float v = acc[m][n][j] + bv;
        if (MODE == 0) {
          ((unsigned short*)Cv)[(size_t)row * N + col] = f2bf(v);
        } else {
          v += resid[(size_t)row * N + col];
          ((float*)Cv)[(size_t)row * N + col] = v;
        }
      }
    }
  }
}

// ---------------- sequential reservoir scan -------------------------------
// grid = 4 (one block per reservoir r), 1024 threads (16 waves, 4 per SIMD).
// Wave w owns output neurons n in [16w, 16w+16) for all 4 batches.
// Batch b sits at MFMA A/C row 4b, so C row 4b = (lq=b, j=0): every lane
// owns exactly 1 output (batch lq, neuron 16*wave+lr).
// 4 waves/SIMD give TLP to hide barrier/LDS/MFMA latency.
__global__ __launch_bounds__(1024, 4)
void scan_kernel(const unsigned short* __restrict__ x,   // [B*T][1024] bf16
                 const float* __restrict__ prev,          // [B][1024] f32
                 const float* __restrict__ w_res,         // [4][256][256] f32
                 unsigned short* __restrict__ states,     // [B*T][1024] bf16
                 float* __restrict__ final_out) {         // [B][1024] f32
  const int r    = blockIdx.x;
  const int tid  = threadIdx.x;
  const int wave = tid >> 6, lane = tid & 63;
  const int lq   = lane >> 4, lr = lane & 15;

  // [buf][batch][neuron], stride 272 u16 so the 16 active A-read lanes land
  // pairwise <=2-way on banks (2-way is free, m136).
  __shared__ unsigned short st_lds[2][4][272];

  // --- W fragments: bw[kt]; lane holds B[k=kt*32+lq*8+i][n=16*wave+lr]
  //     where B[j][n] = W[n][j] = w_res[r][n][j]
  BF8 bw[8];
  {
    const float* wbase = w_res + (size_t)r * 65536 + (size_t)(wave * 16 + lr) * 256;
    #pragma unroll
    for (int kt = 0; kt < 8; ++kt) {
      const float* s = wbase + kt * 32 + lq * 8;
      const float4 f0 = *(const float4*)s;
      const float4 f1 = *(const float4*)(s + 4);
      BF8 t;
      t.u[0]=f2bf(f0.x); t.u[1]=f2bf(f0.y); t.u[2]=f2bf(f0.z); t.u[3]=f2bf(f0.w);
      t.u[4]=f2bf(f1.x); t.u[5]=f2bf(f1.y); t.u[6]=f2bf(f1.z); t.u[7]=f2bf(f1.w);
      bw[kt] = t;
    }
  }

  // --- init state LDS buffer 0 with prev_state (1024 threads, 1 elem each)
  {
    const int b = tid >> 8, j = tid & 255;
    st_lds[0][b][j] = f2bf(prev[b * 1024 + r * 256 + j]);
  }

  // --- per-lane f32 master state + prefetched x: batch lq, neuron 16w+lr
  const int nidx = wave * 16 + lr;
  float stf = prev[lq * 1024 + r * 256 + nidx];
  const unsigned short* xp = x      + (size_t)lq * T_LEN * 1024 + r * 256 + nidx;
  unsigned short*       sp = states + (size_t)lq * T_LEN * 1024 + r * 256 + nidx;
  float xr = bf2f(xp[0]);   // x_0 in flight

  // A fragments: lane&15 = row; rows {0,4,8,12} carry batch row/4, rest 0.
  bf16x8 af[8] = {};
  const bool aload = (lr & 3) == 0;
  const int  ab    = lr >> 2;
  int cur = 0;

  for (int t = 0; t < T_LEN; ++t) {
    // drain LDS only; keep global loads/stores in flight across the barrier
    asm volatile("s_waitcnt lgkmcnt(0)" ::: "memory");
    __builtin_amdgcn_s_barrier();
    asm volatile("" ::: "memory");

    // consume prefetched x_t, immediately issue load of x_{t+1}
    const float x_use = xr;
    const int adv = (t + 1 < T_LEN) ? 1024 : 0;
    xp += adv;
    xr = bf2f(xp[0]);

    #pragma unroll
    for (int kt = 0; kt < 8; ++kt) {
      if (aload) {
        BF8 tmp;
        tmp.q = *(const uint4*)&st_lds[cur][ab][kt * 32 + lq * 8];
        af[kt] = tmp.v;
      }
    }

    // 2 independent accumulator chains, depth 4 each
    f32x4 acc0 = {x_use, 0.f, 0.f, 0.f};
    f32x4 acc1 = {0.f, 0.f, 0.f, 0.f};
    #pragma unroll
    for (int kt = 0; kt < 4; ++kt) {
      acc0 = __builtin_amdgcn_mfma_f32_16x16x32_bf16(af[kt],     bw[kt].v,     acc0, 0, 0, 0);
      acc1 = __builtin_amdgcn_mfma_f32_16x16x32_bf16(af[kt + 4], bw[kt + 4].v, acc1, 0, 0, 0);
    }

    // state update (all 64 lanes, 1 value each)
    const int nxt = cur ^ 1;
    const float pre = acc0[0] + acc1[0];
    const float e   = __expf(2.0f * pre);
    const float th  = 1.0f - 2.0f / (e + 1.0f);   // tanh, saturates safely
    const float ns  = 0.9f * stf + 0.1f * th;
    stf = ns;
    const unsigned short h = f2bf(ns);
    st_lds[nxt][lq][nidx] = h;
    sp[0] = h;
    sp += 1024;
    cur = nxt;
  }

  // final state (f32) from register copy
  final_out[lq * 1024 + r * 256 + nidx] = stf;
}

// ---------------- in-place RMSNorm over rows of 2048 ----------------------
__global__ __launch_bounds__(256, 4)
void rmsnorm_kernel(float* __restrict__ y, const float* __restrict__ lnw) {
  const int row = blockIdx.x;
  float* p = y + (size_t)row * 2048;
  const int tid = threadIdx.x;
  const int wave = tid >> 6, lane = tid & 63;
  float4 a = ((const float4*)p)[tid * 2];
  float4 b = ((const float4*)p)[tid * 2 + 1];
  float ss = a.x*a.x + a.y*a.y + a.z*a.z + a.w*a.w
           + b.x*b.x + b.y*b.y + b.z*b.z + b.w*b.w;
  #pragma unroll
  for (int m = 32; m >= 1; m >>= 1) ss += __shfl_xor(ss, m, 64);
  __shared__ float red[4];
  if (lane == 0) red[wave] = ss;
  __syncthreads();
  const float tot = red[0] + red[1] + red[2] + red[3];
  const float sc = rsqrtf(tot * (1.0f / 2048.0f) + 1e-6f);
  const float4 la = ((const float4*)lnw)[tid * 2];
  const float4 lb = ((const float4*)lnw)[tid * 2 + 1];
  a.x *= sc * la.x; a.y *= sc * la.y; a.z *= sc * la.z; a.w *= sc * la.w;
  b.x *= sc * lb.x; b.y *= sc * lb.y; b.z *= sc * lb.z; b.w *= sc * lb.w;
  ((float4*)p)[tid * 2] = a;
  ((float4*)p)[tid * 2 + 1] = b;
}

// --------------------------------------------------------------------------
extern "C" void kernel_launch(void* const* d_in, const int* in_sizes, int n_in,
                              void* d_out, int out_size, void* d_ws, size_t ws_size,
                              hipStream_t stream) {
  const float* hs    = (const float*)d_in[0];  // [4,2048,2048]
  const float* prev  = (const float*)d_in[1];  // [4,1024]
  const float* w_in  = (const float*)d_in[2];  // [2048,1024]
  const float* b_in  = (const float*)d_in[3];  // [1024]
  const float* w_res = (const float*)d_in[4];  // [4,256,256]
  const float* w_out = (const float*)d_in[5];  // [1024,2048]
  const float* b_out = (const float*)d_in[6];  // [2048]
  const float* ln_w  = (const float*)d_in[7];  // [2048]
  float* out = (float*)d_out;                  // y[8192*2048] then final[4096]

  char* ws = (char*)d_ws;
  unsigned short* hs_bf   = (unsigned short*)(ws);              // 32 MiB
  unsigned short* x_bf    = (unsigned short*)(ws + 33554432);   // 16 MiB
  unsigned short* states  = (unsigned short*)(ws + 50331648);   // 16 MiB
  unsigned short* w_in_t  = (unsigned short*)(ws + 67108864);   //  4 MiB
  unsigned short* w_out_t = (unsigned short*)(ws + 71303168);   //  4 MiB

  // 1. convert hidden_states to bf16
  conv_bf16_kernel<<<dim3(8192), dim3(256), 0, stream>>>(hs, hs_bf, 2097152);
  // 2. transposed bf16 weights (K-major for MFMA B-fragments)
  conv_T_kernel<<<dim3(1024), dim3(256), 0, stream>>>(w_in,  w_in_t,  1024, 2048);
  conv_T_kernel<<<dim3(1024), dim3(256), 0, stream>>>(w_out, w_out_t, 2048, 1024);
  // 3. x = hs @ w_in + b_in   (bf16 out)
  gemm_bt_kernel<0><<<dim3(8, 64), dim3(256), 0, stream>>>(
      hs_bf, w_in_t, b_in, nullptr, (void*)x_bf, 8192, 1024, 2048);
  // 4. sequential reservoir scan (writes states bf16 + final_state f32)
  scan_kernel<<<dim3(4), dim3(1024), 0, stream>>>(
      x_bf, prev, w_res, states, out + 16777216);
  // 5. y_pre = hs + states @ w_out + b_out  (f32, into d_out)
  gemm_bt_kernel<1><<<dim3(16, 64), dim3(256), 0, stream>>>(
      states, w_out_t, b_out, hs, (void*)out, 8192, 2048, 1024);
  // 6. in-place RMSNorm * ln_w
  rmsnorm_kernel<<<dim3(8192), dim3(256), 0, stream>>>(out, ln_w);
}

// Round 9
// 1435.956 us; speedup vs baseline: 3.1103x; 1.0024x over previous
//
#include <hip/hip_runtime.h>
#include <stdint.h>

#define T_LEN 2048

typedef __bf16 bf16x8 __attribute__((ext_vector_type(8)));
typedef float  f32x4  __attribute__((ext_vector_type(4)));

typedef const __attribute__((address_space(1))) void* as1_cvp;
typedef __attribute__((address_space(3))) void* as3_vp;

union BF8 { unsigned short u[8]; bf16x8 v; uint4 q; };

__device__ __forceinline__ unsigned short f2bf(float f) {
  unsigned int u = __float_as_uint(f);
  u += 0x7FFFu + ((u >> 16) & 1u);            // RNE
  return (unsigned short)(u >> 16);
}
__device__ __forceinline__ float bf2f(unsigned short h) {
  return __uint_as_float(((unsigned int)h) << 16);
}

// ---------------- f32 -> bf16 bulk convert (8 elems/thread) ----------------
__global__ void conv_bf16_kernel(const float* __restrict__ in,
                                 unsigned short* __restrict__ out, int n8) {
  const int i = blockIdx.x * 256 + threadIdx.x;
  if (i >= n8) return;
  const float4 a = ((const float4*)in)[i * 2];
  const float4 b = ((const float4*)in)[i * 2 + 1];
  BF8 t;
  t.u[0]=f2bf(a.x); t.u[1]=f2bf(a.y); t.u[2]=f2bf(a.z); t.u[3]=f2bf(a.w);
  t.u[4]=f2bf(b.x); t.u[5]=f2bf(b.y); t.u[6]=f2bf(b.z); t.u[7]=f2bf(b.w);
  ((uint4*)out)[i] = t.q;
}

// ------------- transpose+convert: out[n][k] (bf16) = in[k][n] (f32) --------
__global__ void conv_T_kernel(const float* __restrict__ in,
                              unsigned short* __restrict__ out, int N, int K) {
  const int k8 = K >> 3;
  const int t = blockIdx.x * 256 + threadIdx.x;
  if (t >= N * k8) return;
  const int n = t / k8, k0 = (t - n * k8) << 3;
  BF8 o;
  #pragma unroll
  for (int i = 0; i < 8; ++i) o.u[i] = f2bf(in[(size_t)(k0 + i) * N + n]);
  *(uint4*)&out[(size_t)n * K + k0] = o.q;
}

// ---------------- bf16 GEMM: C[M,N] = A[M,K] * Bt[N,K]^T (+bias[,+resid]) ---
// MODE 0: C is bf16, no residual.  MODE 1: C is f32, += resid[row*N+col].
template<int MODE>
__global__ __launch_bounds__(256, 2)
void gemm_bt_kernel(const unsigned short* __restrict__ A,
                    const unsigned short* __restrict__ Bt,
                    const float* __restrict__ bias,
                    const float* __restrict__ resid,
                    void* __restrict__ Cv,
                    int M, int N, int K) {
  __shared__ unsigned short As[128 * 64];
  __shared__ unsigned short Bs[128 * 64];
  const int tid  = threadIdx.x;
  const int wave = tid >> 6, lane = tid & 63;
  const int lq = lane >> 4, lr = lane & 15;
  const int wr = wave >> 1, wc = wave & 1;
  const int m0 = blockIdx.y * 128, n0 = blockIdx.x * 128;

  f32x4 acc[4][4] = {};

  for (int k0 = 0; k0 < K; k0 += 64) {
    #pragma unroll
    for (int i = 0; i < 4; ++i) {
      const int c = i * 256 + tid;                 // 16B chunk id, 0..1023
      const int crow = c >> 3, ccol = (c & 7) << 3;
      const unsigned short* ga = A  + (size_t)(m0 + crow) * K + (k0 + ccol);
      const unsigned short* gb = Bt + (size_t)(n0 + crow) * K + (k0 + ccol);
      __builtin_amdgcn_global_load_lds((as1_cvp)(const void*)ga,
          (as3_vp)(void*)(As + (i * 256 + wave * 64) * 8), 16, 0, 0);
      __builtin_amdgcn_global_load_lds((as1_cvp)(const void*)gb,
          (as3_vp)(void*)(Bs + (i * 256 + wave * 64) * 8), 16, 0, 0);
    }
    __syncthreads();
    #pragma unroll
    for (int kt = 0; kt < 2; ++kt) {
      BF8 a[4], b[4];
      #pragma unroll
      for (int m = 0; m < 4; ++m)
        a[m].q = *(const uint4*)&As[(wr * 64 + m * 16 + lr) * 64 + kt * 32 + lq * 8];
      #pragma unroll
      for (int n = 0; n < 4; ++n)
        b[n].q = *(const uint4*)&Bs[(wc * 64 + n * 16 + lr) * 64 + kt * 32 + lq * 8];
      #pragma unroll
      for (int m = 0; m < 4; ++m)
        #pragma unroll
        for (int n = 0; n < 4; ++n)
          acc[m][n] = __builtin_amdgcn_mfma_f32_16x16x32_bf16(a[m].v, b[n].v, acc[m][n], 0, 0, 0);
    }
    __syncthreads();
  }

  #pragma unroll
  for (int m = 0; m < 4; ++m) {
    #pragma unroll
    for (int n = 0; n < 4; ++n) {
      const int col = n0 + wc * 64 + n * 16 + lr;
      const float bv = bias[col];
      #pragma unroll
      for (int j = 0; j < 4; ++j) {
        const int row = m0 + wr * 64 + m * 16 + lq * 4 + j;
        float v = acc[m][n][j] + bv;
        if (MODE == 0) {
          ((unsigned short*)Cv)[(size_t)row * N + col] = f2bf(v);
        } else {
          v += resid[(size_t)row * N + col];
          ((float*)Cv)[(size_t)row * N + col] = v;
        }
      }
    }
  }
}

// ---------------- sequential reservoir scan -------------------------------
// grid = 4 (one block per reservoir r), 1024 threads (16 waves, 4 per SIMD).
// Wave w owns output neurons n in [16w, 16w+16) for all 4 batches.
// Batch b sits at MFMA A/C row 4b, so C row 4b = (lq=b, j=0): every lane
// owns exactly 1 output (batch lq, neuron 16*wave+lr).
// x prefetch: load raw ushort one step ahead; bf2f at consume time so the
// vmcnt wait lands a full step after issue (no synchronized stall).
__global__ __launch_bounds__(1024, 4)
void scan_kernel(const unsigned short* __restrict__ x,   // [B*T][1024] bf16
                 const float* __restrict__ prev,          // [B][1024] f32
                 const float* __restrict__ w_res,         // [4][256][256] f32
                 unsigned short* __restrict__ states,     // [B*T][1024] bf16
                 float* __restrict__ final_out) {         // [B][1024] f32
  const int r    = blockIdx.x;
  const int tid  = threadIdx.x;
  const int wave = tid >> 6, lane = tid & 63;
  const int lq   = lane >> 4, lr = lane & 15;

  // [buf][batch][neuron], stride 272 u16 so the 16 active A-read lanes land
  // pairwise <=2-way on banks (2-way is free, m136).
  __shared__ unsigned short st_lds[2][4][272];

  // --- W fragments: bw[kt]; lane holds B[k=kt*32+lq*8+i][n=16*wave+lr]
  //     where B[j][n] = W[n][j] = w_res[r][n][j]
  BF8 bw[8];
  {
    const float* wbase = w_res + (size_t)r * 65536 + (size_t)(wave * 16 + lr) * 256;
    #pragma unroll
    for (int kt = 0; kt < 8; ++kt) {
      const float* s = wbase + kt * 32 + lq * 8;
      const float4 f0 = *(const float4*)s;
      const float4 f1 = *(const float4*)(s + 4);
      BF8 t;
      t.u[0]=f2bf(f0.x); t.u[1]=f2bf(f0.y); t.u[2]=f2bf(f0.z); t.u[3]=f2bf(f0.w);
      t.u[4]=f2bf(f1.x); t.u[5]=f2bf(f1.y); t.u[6]=f2bf(f1.z); t.u[7]=f2bf(f1.w);
      bw[kt] = t;
    }
  }

  // --- init state LDS buffer 0 with prev_state (1024 threads, 1 elem each)
  {
    const int b = tid >> 8, j = tid & 255;
    st_lds[0][b][j] = f2bf(prev[b * 1024 + r * 256 + j]);
  }

  // --- per-lane f32 master state: batch lq, neuron 16w+lr
  const int nidx = wave * 16 + lr;
  float stf = prev[lq * 1024 + r * 256 + nidx];
  const unsigned short* xp = x      + (size_t)lq * T_LEN * 1024 + r * 256 + nidx;
  unsigned short*       sp = states + (size_t)lq * T_LEN * 1024 + r * 256 + nidx;
  unsigned short xraw = xp[0];      // x_0 issued; converted at first use

  // A fragments: lane&15 = row; rows {0,4,8,12} carry batch row/4, rest 0.
  bf16x8 af[8] = {};
  const bool aload = (lr & 3) == 0;
  const int  ab    = lr >> 2;
  int cur = 0;

  for (int t = 0; t < T_LEN; ++t) {
    // drain LDS only; keep global loads/stores in flight across the barrier
    asm volatile("s_waitcnt lgkmcnt(0)" ::: "memory");
    __builtin_amdgcn_s_barrier();
    asm volatile("" ::: "memory");

    // A fragments from current state buffer
    #pragma unroll
    for (int kt = 0; kt < 8; ++kt) {
      if (aload) {
        BF8 tmp;
        tmp.q = *(const uint4*)&st_lds[cur][ab][kt * 32 + lq * 8];
        af[kt] = tmp.v;
      }
    }

    // consume x_t (loaded one step ago -> vmcnt wait is ~free)
    const float x_use = bf2f(xraw);
    if (t + 1 < T_LEN) xp += 1024;

    // 2 independent accumulator chains, depth 4 each
    f32x4 acc0 = {x_use, 0.f, 0.f, 0.f};
    f32x4 acc1 = {0.f, 0.f, 0.f, 0.f};
    #pragma unroll
    for (int kt = 0; kt < 4; ++kt) {
      acc0 = __builtin_amdgcn_mfma_f32_16x16x32_bf16(af[kt],     bw[kt].v,     acc0, 0, 0, 0);
      acc1 = __builtin_amdgcn_mfma_f32_16x16x32_bf16(af[kt + 4], bw[kt + 4].v, acc1, 0, 0, 0);
    }

    // state update (all 64 lanes, 1 value each)
    const int nxt = cur ^ 1;
    const float pre = acc0[0] + acc1[0];
    const float e   = __expf(2.0f * pre);
    const float th  = 1.0f - __fdividef(2.0f, e + 1.0f);  // tanh, saturates safely
    const float ns  = 0.9f * stf + 0.1f * th;
    stf = ns;
    const unsigned short h = f2bf(ns);
    st_lds[nxt][lq][nidx] = h;
    xraw = xp[0];            // issue x_{t+1}; stays in flight across the barrier
    sp[0] = h;               // store issued after the load (wait stays cheap)
    sp += 1024;
    cur = nxt;
  }

  // final state (f32) from register copy
  final_out[lq * 1024 + r * 256 + nidx] = stf;
}

// ---------------- in-place RMSNorm over rows of 2048 ----------------------
__global__ __launch_bounds__(256, 4)
void rmsnorm_kernel(float* __restrict__ y, const float* __restrict__ lnw) {
  const int row = blockIdx.x;
  float* p = y + (size_t)row * 2048;
  const int tid = threadIdx.x;
  const int wave = tid >> 6, lane = tid & 63;
  float4 a = ((const float4*)p)[tid * 2];
  float4 b = ((const float4*)p)[tid * 2 + 1];
  float ss = a.x*a.x + a.y*a.y + a.z*a.z + a.w*a.w
           + b.x*b.x + b.y*b.y + b.z*b.z + b.w*b.w;
  #pragma unroll
  for (int m = 32; m >= 1; m >>= 1) ss += __shfl_xor(ss, m, 64);
  __shared__ float red[4];
  if (lane == 0) red[wave] = ss;
  __syncthreads();
  const float tot = red[0] + red[1] + red[2] + red[3];
  const float sc = rsqrtf(tot * (1.0f / 2048.0f) + 1e-6f);
  const float4 la = ((const float4*)lnw)[tid * 2];
  const float4 lb = ((const float4*)lnw)[tid * 2 + 1];
  a.x *= sc * la.x; a.y *= sc * la.y; a.z *= sc * la.z; a.w *= sc * la.w;
  b.x *= sc * lb.x; b.y *= sc * lb.y; b.z *= sc * lb.z; b.w *= sc * lb.w;
  ((float4*)p)[tid * 2] = a;
  ((float4*)p)[tid * 2 + 1] = b;
}

// --------------------------------------------------------------------------
extern "C" void kernel_launch(void* const* d_in, const int* in_sizes, int n_in,
                              void* d_out, int out_size, void* d_ws, size_t ws_size,
                              hipStream_t stream) {
  const float* hs    = (const float*)d_in[0];  // [4,2048,2048]
  const float* prev  = (const float*)d_in[1];  // [4,1024]
  const float* w_in  = (const float*)d_in[2];  // [2048,1024]
  const float* b_in  = (const float*)d_in[3];  // [1024]
  const float* w_res = (const float*)d_in[4];  // [4,256,256]
  const float* w_out = (const float*)d_in[5];  // [1024,2048]
  const float* b_out = (const float*)d_in[6];  // [2048]
  const float* ln_w  = (const float*)d_in[7];  // [2048]
  float* out = (float*)d_out;                  // y[8192*2048] then final[4096]

  char* ws = (char*)d_ws;
  unsigned short* hs_bf   = (unsigned short*)(ws);              // 32 MiB
  unsigned short* x_bf    = (unsigned short*)(ws + 33554432);   // 16 MiB
  unsigned short* states  = (unsigned short*)(ws + 50331648);   // 16 MiB
  unsigned short* w_in_t  = (unsigned short*)(ws + 67108864);   //  4 MiB
  unsigned short* w_out_t = (unsigned short*)(ws + 71303168);   //  4 MiB

  // 1. convert hidden_states to bf16
  conv_bf16_kernel<<<dim3(8192), dim3(256), 0, stream>>>(hs, hs_bf, 2097152);
  // 2. transposed bf16 weights (K-major for MFMA B-fragments)
  conv_T_kernel<<<dim3(1024), dim3(256), 0, stream>>>(w_in,  w_in_t,  1024, 2048);
  conv_T_kernel<<<dim3(1024), dim3(256), 0, stream>>>(w_out, w_out_t, 2048, 1024);
  // 3. x = hs @ w_in + b_in   (bf16 out)
  gemm_bt_kernel<0><<<dim3(8, 64), dim3(256), 0, stream>>>(
      hs_bf, w_in_t, b_in, nullptr, (void*)x_bf, 8192, 1024, 2048);
  // 4. sequential reservoir scan (writes states bf16 + final_state f32)
  scan_kernel<<<dim3(4), dim3(1024), 0, stream>>>(
      x_bf, prev, w_res, states, out + 16777216);
  // 5. y_pre = hs + states @ w_out + b_out  (f32, into d_out)
  gemm_bt_kernel<1><<<dim3(16, 64), dim3(256), 0, stream>>>(
      states, w_out_t, b_out, hs, (void*)out, 8192, 2048, 1024);
  // 6. in-place RMSNorm * ln_w
  rmsnorm_kernel<<<dim3(8192), dim3(256), 0, stream>>>(out, ln_w);
}